// Round 8
// baseline (91.519 us; speedup 1.0000x reference)
//
#include <hip/hip_runtime.h>
#include <math.h>

// Tacotron2 location-sensitive attention, fp32.
// B=64 T=2048 E=512 H=128 DL=1024 CC=32 K=31
// out = [context (B*E=32768), weights (B*T=131072)] fp32, concatenated.
// R8: TRUE flash fusion. enc loads are issued inside the energy p-loop
// (addresses independent of energies) and folded into a running context
// accumulator with online-max rescaling. No serial phase split -> enc
// streaming hides under conv/tanh VALU. k2 combines (unchanged).

#define BB 64
#define TT 2048
#define EE 512
#define HH 128
#define DLL 1024
#define CCC 32
#define KK 31

// ws layout (in floats)
#define WS_FW   0        // fw[128][32]                 -> 4096
#define WS_PL   4096     // pl[64][128]                 -> 8192
#define WS_EN   12288    // energies[64][2048]          -> 131072
#define WS_ST   143360   // stats[64][16][2] (m,s)      -> 2048
#define WS_PART 145472   // partials[64][16][512]       -> 524288

// ---------------------------------------------------------------------------
// k0: blocks 0..2047: one wave per (b,h) dot  pl[b][h] = lstm[b]·W_lstm[h]
//     block 2048: fw[h][k] = sum_c W_loc[h][c]*conv_w[c][k]
// ---------------------------------------------------------------------------
__global__ __launch_bounds__(256) void k0_prep(const float* __restrict__ lstm,
                                               const float* __restrict__ Wl,
                                               const float* __restrict__ cw,
                                               const float* __restrict__ Wloc,
                                               float* __restrict__ ws) {
  const int blk = blockIdx.x;
  const int tid = threadIdx.x;
  if (blk < 2048) {
    const int wave = tid >> 6, lane = tid & 63;
    const int wg = blk * 4 + wave;      // 0..8191
    const int b = wg >> 7, h = wg & 127;
    const float4* wr = (const float4*)(Wl + (size_t)h * DLL);
    const float4* lr = (const float4*)(lstm + (size_t)b * DLL);
    float s = 0.f;
#pragma unroll
    for (int m = 0; m < 4; ++m) {
      float4 a = wr[m * 64 + lane];
      float4 c = lr[m * 64 + lane];
      s += a.x * c.x + a.y * c.y + a.z * c.z + a.w * c.w;
    }
#pragma unroll
    for (int m = 1; m < 64; m <<= 1) s += __shfl_xor(s, m, 64);
    if (lane == 0) ws[WS_PL + b * HH + h] = s;
  } else {
    __shared__ __align__(16) float wl_s[HH * CCC];  // 4096
    __shared__ __align__(16) float cw_s[CCC * KK];  // 992
#pragma unroll
    for (int m = 0; m < 4; ++m)
      ((float4*)wl_s)[tid + 256 * m] = ((const float4*)Wloc)[tid + 256 * m];
    if (tid < 248) ((float4*)cw_s)[tid] = ((const float4*)cw)[tid];
    __syncthreads();
    const int h = tid >> 1;
    const int kbase = (tid & 1) * 16;
    const int kn = (tid & 1) ? 15 : 16;
    for (int kk = 0; kk < kn; ++kk) {
      const int k = kbase + kk;
      float s = 0.f;
#pragma unroll
      for (int c = 0; c < CCC; ++c) s += wl_s[h * CCC + c] * cw_s[c * KK + k];
      ws[WS_FW + h * 32 + k] = s;
    }
    if (tid & 1) ws[WS_FW + h * 32 + 31] = 0.f;  // pad
  }
}

// ---------------------------------------------------------------------------
// k1_fused: per (chunk of 128 t, b), grid (16,64), 4 waves.
// Wave w owns t in [w*32, w*32+32) and ALL 512 e-columns (lane holds float4
// cols lane and lane+64). Per p (4 t): issue 8 enc float4 loads, compute
// energies (conv via fw, tanh, We-dot, butterfly), then online-rescaled
// accumulate. End: cross-wave combine in LDS (fixed order) -> partial+stats.
// ---------------------------------------------------------------------------
__global__ __launch_bounds__(256) void k1_fused(const float* __restrict__ pe,
                                                const float* __restrict__ aw,
                                                const float* __restrict__ We,
                                                const float* __restrict__ enc,
                                                float* __restrict__ ws) {
  const int b = blockIdx.y;
  const int chunk = blockIdx.x;
  const int t0 = chunk * 128;
  const int tid = threadIdx.x;
  const int wave = tid >> 6, lane = tid & 63;

  __shared__ __align__(16) float aw_s[160];   // aw[t0-16 .. t0+143], zero-pad
  __shared__ __align__(16) float comb[2048];  // 4 waves x 512 cols (8 KB)
  __shared__ float sm[4], ss[4];

  if (tid < 160) {
    const int tg = t0 - 16 + tid;
    aw_s[tid] = (tg >= 0 && tg < TT) ? aw[b * TT + tg] : 0.f;
  }

  const int h0 = 2 * lane;
  float fw0[32], fw1[32];
  {
    const float4* f4 = (const float4*)(ws + WS_FW);
#pragma unroll
    for (int m = 0; m < 8; ++m) {
      float4 a = f4[h0 * 8 + m];
      fw0[4 * m + 0] = a.x; fw0[4 * m + 1] = a.y;
      fw0[4 * m + 2] = a.z; fw0[4 * m + 3] = a.w;
      float4 c = f4[h0 * 8 + 8 + m];
      fw1[4 * m + 0] = c.x; fw1[4 * m + 1] = c.y;
      fw1[4 * m + 2] = c.z; fw1[4 * m + 3] = c.w;
    }
  }
  const float2 plv = ((const float2*)(ws + WS_PL + b * HH))[lane];
  const float2 wev = ((const float2*)We)[lane];
  const float2* pe2 = (const float2*)(pe + (size_t)b * TT * HH);
  const float4* enc4 = (const float4*)(enc + ((size_t)b * TT + t0) * EE);

  __syncthreads();

  float om = -3.4e38f, os = 0.f;                       // online softmax state
  float4 acc0 = {0.f, 0.f, 0.f, 0.f};                  // cols 4*lane..+3
  float4 acc1 = {0.f, 0.f, 0.f, 0.f};                  // cols 256+4*lane..+3

#pragma unroll 1
  for (int p = 0; p < 8; ++p) {
    const int tq = wave * 32 + p * 4;  // local quad start (4 t rows)

    // enc loads for this quad: addresses independent of energies ->
    // issue first, consume ~400 VALU ops later (latency hidden).
    float4 ev0[4], ev1[4];
#pragma unroll
    for (int j = 0; j < 4; ++j) {
      ev0[j] = enc4[(size_t)(tq + j) * 128 + lane];
      ev1[j] = enc4[(size_t)(tq + j) * 128 + 64 + lane];
    }

    float2 pv[4];
#pragma unroll
    for (int j = 0; j < 4; ++j)
      pv[j] = pe2[(size_t)(t0 + tq + j) * 64 + lane];

    float w[36];
    const float4* a4 = (const float4*)&aw_s[tq];
#pragma unroll
    for (int m = 0; m < 9; ++m) {
      float4 v = a4[m];
      w[4 * m + 0] = v.x; w[4 * m + 1] = v.y;
      w[4 * m + 2] = v.z; w[4 * m + 3] = v.w;
    }

    float a0[4], a1[4];
#pragma unroll
    for (int j = 0; j < 4; ++j) {
      a0[j] = plv.x + pv[j].x;
      a1[j] = plv.y + pv[j].y;
    }
#pragma unroll
    for (int k = 0; k < 31; ++k) {
      const float f0 = fw0[k], f1 = fw1[k];
#pragma unroll
      for (int j = 0; j < 4; ++j) {
        a0[j] = fmaf(f0, w[1 + j + k], a0[j]);
        a1[j] = fmaf(f1, w[1 + j + k], a1[j]);
      }
    }
    float e[4];
#pragma unroll
    for (int j = 0; j < 4; ++j) {
      const float th0 = 1.f - 2.f / (__expf(2.f * a0[j]) + 1.f);
      const float th1 = 1.f - 2.f / (__expf(2.f * a1[j]) + 1.f);
      e[j] = wev.x * th0 + wev.y * th1;
    }
#pragma unroll
    for (int m = 1; m < 64; m <<= 1) {
#pragma unroll
      for (int j = 0; j < 4; ++j) e[j] += __shfl_xor(e[j], m, 64);
    }
    if (lane == 0)
      *(float4*)&ws[WS_EN + b * TT + t0 + tq] = make_float4(e[0], e[1], e[2], e[3]);

    // online update (all lanes hold identical e[0..3] after butterfly)
    const float mq = fmaxf(fmaxf(e[0], e[1]), fmaxf(e[2], e[3]));
    const float mn = fmaxf(om, mq);
    const float sc = __expf(om - mn);     // 0 on first iter (om=-inf)
    float wj[4];
#pragma unroll
    for (int j = 0; j < 4; ++j) wj[j] = __expf(e[j] - mn);
    os = os * sc + wj[0] + wj[1] + wj[2] + wj[3];
    acc0.x *= sc; acc0.y *= sc; acc0.z *= sc; acc0.w *= sc;
    acc1.x *= sc; acc1.y *= sc; acc1.z *= sc; acc1.w *= sc;
#pragma unroll
    for (int j = 0; j < 4; ++j) {
      acc0.x = fmaf(wj[j], ev0[j].x, acc0.x);
      acc0.y = fmaf(wj[j], ev0[j].y, acc0.y);
      acc0.z = fmaf(wj[j], ev0[j].z, acc0.z);
      acc0.w = fmaf(wj[j], ev0[j].w, acc0.w);
      acc1.x = fmaf(wj[j], ev1[j].x, acc1.x);
      acc1.y = fmaf(wj[j], ev1[j].y, acc1.y);
      acc1.z = fmaf(wj[j], ev1[j].z, acc1.z);
      acc1.w = fmaf(wj[j], ev1[j].w, acc1.w);
    }
    om = mn;
  }

  // cross-wave combine: block max, rescale, fixed-order sum
  if (lane == 0) { sm[wave] = om; ss[wave] = os; }
  __syncthreads();
  const float mb = fmaxf(fmaxf(sm[0], sm[1]), fmaxf(sm[2], sm[3]));
  const float scw = __expf(om - mb);
  acc0.x *= scw; acc0.y *= scw; acc0.z *= scw; acc0.w *= scw;
  acc1.x *= scw; acc1.y *= scw; acc1.z *= scw; acc1.w *= scw;
  ((float4*)comb)[wave * 128 + lane] = acc0;
  ((float4*)comb)[wave * 128 + 64 + lane] = acc1;
  __syncthreads();
  {
    // thread tid sums float2 column over 4 waves (fixed order)
    const float2* c2 = (const float2*)comb;
    float2 s = c2[tid];
#pragma unroll
    for (int w2 = 1; w2 < 4; ++w2) {
      const float2 v = c2[w2 * 256 + tid];
      s.x += v.x;
      s.y += v.y;
    }
    ((float2*)(ws + WS_PART))[(size_t)(b * 16 + chunk) * 256 + tid] = s;
  }
  if (tid == 0) {
    const float sb = ss[0] * __expf(sm[0] - mb) + ss[1] * __expf(sm[1] - mb) +
                     ss[2] * __expf(sm[2] - mb) + ss[3] * __expf(sm[3] - mb);
    float* st = ws + WS_ST + (b * 16 + chunk) * 2;
    st[0] = mb;
    st[1] = sb;
  }
}

// ---------------------------------------------------------------------------
// k2_combine: per b: global (m, S) from 16 chunk stats; weights from raw
// energies; ctx = sum_c exp(m_c - m) * partial_c / S (fixed order). 64 blocks.
// ---------------------------------------------------------------------------
__global__ __launch_bounds__(256) void k2_combine(const float* __restrict__ ws,
                                                  float* __restrict__ wts,
                                                  float* __restrict__ ctx) {
  const int b = blockIdx.x;
  const int tid = threadIdx.x;

  const float* st = ws + WS_ST + b * 32;
  float mb = -3.4e38f;
#pragma unroll
  for (int c = 0; c < 16; ++c) mb = fmaxf(mb, st[2 * c]);
  float S = 0.f;
#pragma unroll
  for (int c = 0; c < 16; ++c) S += st[2 * c + 1] * __expf(st[2 * c] - mb);
  const float inv = 1.f / S;

  __shared__ float esc[16];
  if (tid < 16) esc[tid] = __expf(st[2 * tid] - mb) * inv;
  __syncthreads();

  // weights: 2048 per b
  const float4* en4 = (const float4*)(ws + WS_EN + (size_t)b * TT);
  float4* w4 = (float4*)(wts + (size_t)b * TT);
#pragma unroll
  for (int j = 0; j < 2; ++j) {
    const float4 e = en4[tid * 2 + j];
    float4 w;
    w.x = __expf(e.x - mb) * inv;
    w.y = __expf(e.y - mb) * inv;
    w.z = __expf(e.z - mb) * inv;
    w.w = __expf(e.w - mb) * inv;
    w4[tid * 2 + j] = w;
  }

  // ctx: 512 per b; thread owns float2 column
  const float2* p2 = (const float2*)(ws + WS_PART) + (size_t)b * 16 * 256 + tid;
  float2 s = {0.f, 0.f};
#pragma unroll
  for (int c = 0; c < 16; ++c) {
    const float2 v = p2[c * 256];
    s.x = fmaf(esc[c], v.x, s.x);
    s.y = fmaf(esc[c], v.y, s.y);
  }
  ((float2*)ctx)[b * 256 + tid] = s;
}

// ---------------------------------------------------------------------------
extern "C" void kernel_launch(void* const* d_in, const int* in_sizes, int n_in,
                              void* d_out, int out_size, void* d_ws, size_t ws_size,
                              hipStream_t stream) {
  const float* enc  = (const float*)d_in[0];  // [B,T,E]
  const float* pe   = (const float*)d_in[1];  // [B,T,H]
  const float* lstm = (const float*)d_in[2];  // [B,1,DL]
  const float* awc  = (const float*)d_in[3];  // [B,T]
  const float* Wl   = (const float*)d_in[4];  // [H,DL]
  const float* cw   = (const float*)d_in[5];  // [CC,1,K]
  const float* Wloc = (const float*)d_in[6];  // [H,CC]
  const float* We   = (const float*)d_in[7];  // [1,H]

  float* out = (float*)d_out;
  float* ctx = out;            // [B,E]
  float* wts = out + BB * EE;  // [B,T]
  float* ws = (float*)d_ws;

  k0_prep<<<2049, 256, 0, stream>>>(lstm, Wl, cw, Wloc, ws);
  k1_fused<<<dim3(16, BB), 256, 0, stream>>>(pe, awc, We, enc, ws);
  k2_combine<<<BB, 256, 0, stream>>>(ws, wts, ctx);
}

// Round 9
// 86.496 us; speedup vs baseline: 1.0581x; 1.0581x over previous
//
#include <hip/hip_runtime.h>
#include <math.h>

// Tacotron2 location-sensitive attention, fp32.
// B=64 T=2048 E=512 H=128 DL=1024 CC=32 K=31
// out = [context (B*E=32768), weights (B*T=131072)] fp32, concatenated.
// R9: R7 phase-split structure, but phase A transposed: ONE LANE = ONE T.
// fw via wave-uniform LDS broadcast (no 64-reg fw in VGPRs), no per-iter
// butterfly, coalesced energy writes, ILP-2 conv chains. Phase B = simple
// column-streaming of enc. k0 prep / k2 combine unchanged.

#define BB 64
#define TT 2048
#define EE 512
#define HH 128
#define DLL 1024
#define CCC 32
#define KK 31

// ws layout (in floats)
#define WS_FW   0        // fw[128][32] (col 31 = 0 pad)  -> 4096
#define WS_PL   4096     // pl[64][128]                   -> 8192
#define WS_EN   12288    // energies[64][2048]            -> 131072
#define WS_ST   143360   // stats[64][16][2] (m,s)        -> 2048
#define WS_PART 145472   // partials[64][16][512]         -> 524288

// ---------------------------------------------------------------------------
// k0: blocks 0..2047: one wave per (b,h) dot  pl[b][h] = lstm[b]·W_lstm[h]
//     block 2048: fw[h][k] = sum_c W_loc[h][c]*conv_w[c][k]
// ---------------------------------------------------------------------------
__global__ __launch_bounds__(256) void k0_prep(const float* __restrict__ lstm,
                                               const float* __restrict__ Wl,
                                               const float* __restrict__ cw,
                                               const float* __restrict__ Wloc,
                                               float* __restrict__ ws) {
  const int blk = blockIdx.x;
  const int tid = threadIdx.x;
  if (blk < 2048) {
    const int wave = tid >> 6, lane = tid & 63;
    const int wg = blk * 4 + wave;      // 0..8191
    const int b = wg >> 7, h = wg & 127;
    const float4* wr = (const float4*)(Wl + (size_t)h * DLL);
    const float4* lr = (const float4*)(lstm + (size_t)b * DLL);
    float s = 0.f;
#pragma unroll
    for (int m = 0; m < 4; ++m) {
      float4 a = wr[m * 64 + lane];
      float4 c = lr[m * 64 + lane];
      s += a.x * c.x + a.y * c.y + a.z * c.z + a.w * c.w;
    }
#pragma unroll
    for (int m = 1; m < 64; m <<= 1) s += __shfl_xor(s, m, 64);
    if (lane == 0) ws[WS_PL + b * HH + h] = s;
  } else {
    __shared__ __align__(16) float wl_s[HH * CCC];  // 4096
    __shared__ __align__(16) float cw_s[CCC * KK];  // 992
#pragma unroll
    for (int m = 0; m < 4; ++m)
      ((float4*)wl_s)[tid + 256 * m] = ((const float4*)Wloc)[tid + 256 * m];
    if (tid < 248) ((float4*)cw_s)[tid] = ((const float4*)cw)[tid];
    __syncthreads();
    const int h = tid >> 1;
    const int kbase = (tid & 1) * 16;
    const int kn = (tid & 1) ? 15 : 16;
    for (int kk = 0; kk < kn; ++kk) {
      const int k = kbase + kk;
      float s = 0.f;
#pragma unroll
      for (int c = 0; c < CCC; ++c) s += wl_s[h * CCC + c] * cw_s[c * KK + k];
      ws[WS_FW + h * 32 + k] = s;
    }
    if (tid & 1) ws[WS_FW + h * 32 + 31] = 0.f;  // pad (used as k=31 with w=junk)
  }
}

// ---------------------------------------------------------------------------
// k1_fused: grid (16,64), 128 threads (2 waves). Chunk = 128 t.
// Phase A (lane = one t): e[t] = sum_h We[h]*tanh(pl[h] + pe[t][h] + conv_t[h])
//   conv via 31-reg aw window (per lane) x fw[h][*] (LDS broadcast).
// Stats (m_c, s_c) via one end-of-phase butterfly. Phase B: thread = one
// float4 col, stream 128 enc rows weighted by exp(e - m_c) -> partial.
// ---------------------------------------------------------------------------
__global__ __launch_bounds__(128) void k1_fused(const float* __restrict__ pe,
                                                const float* __restrict__ aw,
                                                const float* __restrict__ We,
                                                const float* __restrict__ enc,
                                                float* __restrict__ ws) {
  const int b = blockIdx.y;
  const int chunk = blockIdx.x;
  const int t0 = chunk * 128;
  const int tid = threadIdx.x;       // 0..127
  const int wave = tid >> 6, lane = tid & 63;

  __shared__ __align__(16) float fw_s[HH * 32];  // 16 KB
  __shared__ __align__(16) float aw_s[160];
  __shared__ float pl_s[128];
  __shared__ float we_s[128];
  __shared__ float w_chunk[128];
  __shared__ float sm[2], ss[2];

  // stage fw (1024 float4 / 128 thr = 8 each), aw window, pl, We
  {
    const float4* src = (const float4*)(ws + WS_FW);
    float4* dst = (float4*)fw_s;
#pragma unroll
    for (int i = 0; i < 8; ++i) dst[tid + 128 * i] = src[tid + 128 * i];
  }
  {
    int tg = t0 - 16 + tid;
    aw_s[tid] = (tg >= 0 && tg < TT) ? aw[b * TT + tg] : 0.f;
    if (tid < 32) {
      tg = t0 + 112 + tid;
      aw_s[128 + tid] = (tg >= 0 && tg < TT) ? aw[b * TT + tg] : 0.f;
    }
  }
  pl_s[tid] = ws[WS_PL + b * HH + tid];
  we_s[tid] = We[tid];
  __syncthreads();

  // ---- Phase A: lane owns t = t0 + tid ----
  float wreg[32];
#pragma unroll
  for (int k = 0; k < 32; ++k) wreg[k] = aw_s[tid + 1 + k];

  const float4* pr4 = (const float4*)(pe + ((size_t)b * TT + t0 + tid) * HH);
  float e_acc = 0.f;

#pragma unroll 1
  for (int h0 = 0; h0 < 128; h0 += 16) {
    float4 ptv[4];
#pragma unroll
    for (int i = 0; i < 4; ++i) ptv[i] = pr4[(h0 >> 2) + i];
    float pts[16];
#pragma unroll
    for (int i = 0; i < 4; ++i) {
      pts[4 * i + 0] = ptv[i].x; pts[4 * i + 1] = ptv[i].y;
      pts[4 * i + 2] = ptv[i].z; pts[4 * i + 3] = ptv[i].w;
    }
#pragma unroll 2
    for (int hh = 0; hh < 16; ++hh) {
      const int h = h0 + hh;
      const float4* fr = (const float4*)&fw_s[h * 32];  // broadcast reads
      float a0 = pl_s[h] + pts[hh];
      float a1 = 0.f;
#pragma unroll
      for (int q = 0; q < 8; ++q) {
        const float4 f = fr[q];
        a0 = fmaf(f.x, wreg[4 * q + 0], a0);
        a1 = fmaf(f.y, wreg[4 * q + 1], a1);
        a0 = fmaf(f.z, wreg[4 * q + 2], a0);
        a1 = fmaf(f.w, wreg[4 * q + 3], a1);  // q=7: f.w = fw pad 0
      }
      const float x = a0 + a1;
      const float th = 1.f - 2.f / (__expf(2.f * x) + 1.f);
      e_acc = fmaf(we_s[h], th, e_acc);
    }
  }

  // coalesced energy write
  ws[WS_EN + b * TT + t0 + tid] = e_acc;

  // wave stats -> block stats
  float m = e_acc;
#pragma unroll
  for (int s = 1; s < 64; s <<= 1) m = fmaxf(m, __shfl_xor(m, s, 64));
  float p = __expf(e_acc - m);
#pragma unroll
  for (int s = 1; s < 64; s <<= 1) p += __shfl_xor(p, s, 64);
  if (lane == 0) { sm[wave] = m; ss[wave] = p; }
  __syncthreads();
  const float mb = fmaxf(sm[0], sm[1]);
  if (tid == 0) {
    const float sb = ss[0] * __expf(sm[0] - mb) + ss[1] * __expf(sm[1] - mb);
    float* st = ws + WS_ST + (b * 16 + chunk) * 2;
    st[0] = mb;
    st[1] = sb;
  }
  w_chunk[tid] = __expf(e_acc - mb);
  __syncthreads();

  // ---- Phase B: thread owns float4 column tid; stream 128 rows ----
  const float4* enc4 = (const float4*)(enc + ((size_t)b * TT + t0) * EE);
  float4 acc0 = {0.f, 0.f, 0.f, 0.f}, acc1 = {0.f, 0.f, 0.f, 0.f};
#pragma unroll 8
  for (int t = 0; t < 128; ++t) {
    const float w = w_chunk[t];
    const float4 v = enc4[(size_t)t * 128 + tid];
    if (t & 1) {
      acc1.x = fmaf(w, v.x, acc1.x); acc1.y = fmaf(w, v.y, acc1.y);
      acc1.z = fmaf(w, v.z, acc1.z); acc1.w = fmaf(w, v.w, acc1.w);
    } else {
      acc0.x = fmaf(w, v.x, acc0.x); acc0.y = fmaf(w, v.y, acc0.y);
      acc0.z = fmaf(w, v.z, acc0.z); acc0.w = fmaf(w, v.w, acc0.w);
    }
  }
  acc0.x += acc1.x; acc0.y += acc1.y; acc0.z += acc1.z; acc0.w += acc1.w;
  ((float4*)(ws + WS_PART))[(size_t)(b * 16 + chunk) * 128 + tid] = acc0;
}

// ---------------------------------------------------------------------------
// k2_combine: per b: global (m, S) from 16 chunk stats; weights from raw
// energies; ctx = sum_c exp(m_c - m) * partial_c / S (fixed order). 64 blocks.
// ---------------------------------------------------------------------------
__global__ __launch_bounds__(256) void k2_combine(const float* __restrict__ ws,
                                                  float* __restrict__ wts,
                                                  float* __restrict__ ctx) {
  const int b = blockIdx.x;
  const int tid = threadIdx.x;

  const float* st = ws + WS_ST + b * 32;
  float mb = -3.4e38f;
#pragma unroll
  for (int c = 0; c < 16; ++c) mb = fmaxf(mb, st[2 * c]);
  float S = 0.f;
#pragma unroll
  for (int c = 0; c < 16; ++c) S += st[2 * c + 1] * __expf(st[2 * c] - mb);
  const float inv = 1.f / S;

  __shared__ float esc[16];
  if (tid < 16) esc[tid] = __expf(st[2 * tid] - mb) * inv;
  __syncthreads();

  // weights: 2048 per b
  const float4* en4 = (const float4*)(ws + WS_EN + (size_t)b * TT);
  float4* w4 = (float4*)(wts + (size_t)b * TT);
#pragma unroll
  for (int j = 0; j < 2; ++j) {
    const float4 e = en4[tid * 2 + j];
    float4 w;
    w.x = __expf(e.x - mb) * inv;
    w.y = __expf(e.y - mb) * inv;
    w.z = __expf(e.z - mb) * inv;
    w.w = __expf(e.w - mb) * inv;
    w4[tid * 2 + j] = w;
  }

  // ctx: 512 per b; thread owns float2 column
  const float2* p2 = (const float2*)(ws + WS_PART) + (size_t)b * 16 * 256 + tid;
  float2 s = {0.f, 0.f};
#pragma unroll
  for (int c = 0; c < 16; ++c) {
    const float2 v = p2[c * 256];
    s.x = fmaf(esc[c], v.x, s.x);
    s.y = fmaf(esc[c], v.y, s.y);
  }
  ((float2*)ctx)[b * 256 + tid] = s;
}

// ---------------------------------------------------------------------------
extern "C" void kernel_launch(void* const* d_in, const int* in_sizes, int n_in,
                              void* d_out, int out_size, void* d_ws, size_t ws_size,
                              hipStream_t stream) {
  const float* enc  = (const float*)d_in[0];  // [B,T,E]
  const float* pe   = (const float*)d_in[1];  // [B,T,H]
  const float* lstm = (const float*)d_in[2];  // [B,1,DL]
  const float* awc  = (const float*)d_in[3];  // [B,T]
  const float* Wl   = (const float*)d_in[4];  // [H,DL]
  const float* cw   = (const float*)d_in[5];  // [CC,1,K]
  const float* Wloc = (const float*)d_in[6];  // [H,CC]
  const float* We   = (const float*)d_in[7];  // [1,H]

  float* out = (float*)d_out;
  float* ctx = out;            // [B,E]
  float* wts = out + BB * EE;  // [B,T]
  float* ws = (float*)d_ws;

  k0_prep<<<2049, 256, 0, stream>>>(lstm, Wl, cw, Wloc, ws);
  k1_fused<<<dim3(16, BB), 128, 0, stream>>>(pe, awc, We, enc, ws);
  k2_combine<<<BB, 256, 0, stream>>>(ws, wts, ctx);
}